// Round 5
// baseline (140.379 us; speedup 1.0000x reference)
//
#include <hip/hip_runtime.h>
#include <hip/hip_bf16.h>

// Problem constants
constexpr int Bn  = 8;
constexpr int Cn  = 1024;
constexpr int Tn  = 4096;
constexpr int Hn  = 16;
constexpr int Kn  = 15;
constexpr int Fp  = 256;   // padded f dim: row = h*16 + k, k==15 is zero pad

typedef __attribute__((ext_vector_type(8))) short    bf16x8;
typedef __attribute__((ext_vector_type(4))) float    f32x4;

static __device__ __forceinline__ unsigned short f2bf(float f) {
    __hip_bfloat16 h = __float2bfloat16(f);   // round-to-nearest-even
    return *reinterpret_cast<unsigned short*>(&h);
}

// ---------------------------------------------------------------------------
// P1: build padded bf16 W' (256 x 1024) from W (240 x 1024) f32.  (Wp -> d_ws)
// ---------------------------------------------------------------------------
__global__ __launch_bounds__(256)
void lwc_wpad(const float* __restrict__ W, unsigned short* __restrict__ Wp)
{
    const int idx = (blockIdx.x * 256 + threadIdx.x) * 4;  // over 256*1024
    const int m = idx >> 10, c = idx & 1023;
    const int h = m >> 4, k = m & 15;
    float4 v = make_float4(0.f, 0.f, 0.f, 0.f);
    if (k < 15)
        v = *reinterpret_cast<const float4*>(W + ((size_t)(h * 15 + k)) * Cn + c);
    ushort4 o;
    o.x = f2bf(v.x); o.y = f2bf(v.y); o.z = f2bf(v.z); o.w = f2bf(v.w);
    *reinterpret_cast<ushort4*>(Wp + idx) = o;
}

// ---------------------------------------------------------------------------
// FULLY FUSED: transpose-stage + MFMA GEMM + softmax (w -> LDS, f32) + apply.
// grid (Tn/64, Bn) = (64, 8), block 256 (4 waves). LDS: 16 KB staging +
// 60 KB w  = 76 KB -> 2 blocks/CU. w never touches HBM; apply-phase x
// re-reads hit L2/L3 (same tile just streamed).
//
// GEMM: wave wv owns M rows [wv*64, wv*64+64) of W' (heads 4wv..4wv+3);
// K-loop 8 chunks x 128 c, single-buffered LDS, register prefetch.
// LDS B layout [cg][slot=t][8c] bf16, slot ^= (cg&7) both sides (round-4
// verified). Softmax: per-head 16-row fragment; taps k live on lanes
// (lg,r) -> shfl_xor 16/32 reduce. wl[h][k][t] f32, stride 960/head.
// Apply: thread (h=tid>>4, tq=tid&15): 15 taps from LDS into VGPRs,
// 64 channels x 4 t outputs, x windows from global (L3-hit).
// ---------------------------------------------------------------------------
__global__ __launch_bounds__(256, 2)
void lwc_full(const float* __restrict__ x,
              const unsigned short* __restrict__ Wp,
              float* __restrict__ out)
{
    __shared__ __align__(16) unsigned short xs[16 * 64 * 8];   // 16 KiB
    __shared__ __align__(16) float wl[Hn * Kn * 64];           // 60 KiB

    const int tid  = threadIdx.x;
    const int lane = tid & 63;
    const int wv   = tid >> 6;
    const int t0   = blockIdx.x * 64;
    const int b    = blockIdx.y;

    const int lr = lane & 15;
    const int lg = lane >> 4;

    // staging mapping
    const int tcell = tid & 15;        // 4 t's: t0 + tcell*4 + tt
    const int coct  = tid >> 4;        // 8 c's: ck*128 + coct*8 + j
    const float* xbase = x + (size_t)b * Cn * Tn + t0 + tcell * 4;

    f32x4 acc[4][4];
#pragma unroll
    for (int i = 0; i < 4; ++i)
#pragma unroll
        for (int j = 0; j < 4; ++j) acc[i][j] = (f32x4){0.f, 0.f, 0.f, 0.f};

    // prologue: load chunk 0
    float4 ld[8];
#pragma unroll
    for (int j = 0; j < 8; ++j)
        ld[j] = *reinterpret_cast<const float4*>(
            xbase + (size_t)(coct * 8 + j) * Tn);

    const unsigned short* Abase = Wp + ((size_t)(wv * 64 + lr)) * Cn + lg * 8;
    unsigned short* wrow = xs + coct * 512;
    const int csw  = coct & 7;
    const int lrx0 = lr ^ lg;

#pragma unroll 1
    for (int ck = 0; ck < 8; ++ck) {
        // ---- convert + LDS write (ld holds this chunk) ----
#pragma unroll
        for (int tt = 0; tt < 4; ++tt) {
            const int slotw = (tcell * 4 + tt) ^ csw;
            float cf[8] = {0};
#pragma unroll
            for (int j = 0; j < 8; ++j)
                cf[j] = (tt == 0) ? ld[j].x : (tt == 1) ? ld[j].y
                      : (tt == 2) ? ld[j].z : ld[j].w;
            bf16x8 pk;
#pragma unroll
            for (int j = 0; j < 8; ++j) pk[j] = (short)f2bf(cf[j]);
            *reinterpret_cast<bf16x8*>(wrow + slotw * 8) = pk;
        }
        __syncthreads();

        // ---- prefetch next chunk (issue early; overlaps MFMA) ----
        float4 ldn[8];
        if (ck < 7) {
#pragma unroll
            for (int j = 0; j < 8; ++j)
                ldn[j] = *reinterpret_cast<const float4*>(
                    xbase + (size_t)((ck + 1) * 128 + coct * 8 + j) * Tn);
        }

        // ---- MFMA over this chunk: 4 K-steps of 32 ----
        const unsigned short* Apc = Abase + ck * 128;
#pragma unroll
        for (int ks = 0; ks < 4; ++ks) {
            bf16x8 af[4], bfr[4];
            const unsigned short* ap = Apc + ks * 32;
#pragma unroll
            for (int mi = 0; mi < 4; ++mi)
                af[mi] = *reinterpret_cast<const bf16x8*>(ap + (size_t)mi * 16 * Cn);
            const int lrx = lrx0 ^ ((ks & 1) << 2);
            const unsigned short* bp = xs + (ks * 4 + lg) * 512 + lrx * 8;
#pragma unroll
            for (int ni = 0; ni < 4; ++ni)
                bfr[ni] = *reinterpret_cast<const bf16x8*>(bp + ni * 128);
#pragma unroll
            for (int mi = 0; mi < 4; ++mi)
#pragma unroll
                for (int ni = 0; ni < 4; ++ni)
                    acc[mi][ni] = __builtin_amdgcn_mfma_f32_16x16x32_bf16(
                        af[mi], bfr[ni], acc[mi][ni], 0, 0, 0);
        }
        __syncthreads();   // all reads done before next chunk's LDS write

        if (ck < 7) {
#pragma unroll
            for (int j = 0; j < 8; ++j) ld[j] = ldn[j];
        }
    }

    // ---- softmax over k within each head fragment -> wl (f32, in LDS) ----
    const int tcol = lane & 15;
#pragma unroll
    for (int mi = 0; mi < 4; ++mi) {
        const int h = wv * 4 + mi;
        float* hb = wl + h * 960;      // 15*64 floats per head
#pragma unroll
        for (int ni = 0; ni < 4; ++ni) {
            f32x4 v = acc[mi][ni];
            float mx = -3.0e38f;
#pragma unroll
            for (int r = 0; r < 4; ++r)
                if (lg * 4 + r < 15) mx = fmaxf(mx, v[r]);
            mx = fmaxf(mx, __shfl_xor(mx, 16));
            mx = fmaxf(mx, __shfl_xor(mx, 32));
            float e[4], s = 0.f;
#pragma unroll
            for (int r = 0; r < 4; ++r) {
                const int k = lg * 4 + r;
                e[r] = (k < 15) ? __expf(v[r] - mx) : 0.f;
                s += e[r];
            }
            s += __shfl_xor(s, 16);
            s += __shfl_xor(s, 32);
            const float inv = 1.f / s;
#pragma unroll
            for (int r = 0; r < 4; ++r) {
                const int k = lg * 4 + r;
                if (k < 15)
                    hb[k * 64 + ni * 16 + tcol] = e[r] * inv;
            }
        }
    }
    __syncthreads();

    // ---- apply phase: thread (h2, tq) -> 64 channels x 4 t outputs ----
    const int h2 = tid >> 4;           // head 0..15
    const int tq = tid & 15;           // t-quad within tile

    float4 wreg[15];
#pragma unroll
    for (int k = 0; k < 15; ++k)
        wreg[k] = *reinterpret_cast<const float4*>(wl + h2 * 960 + k * 64 + tq * 4);

    const int g0 = t0 + tq * 4 - 8;
    const bool interior = (g0 >= 0) && (g0 + 20 <= Tn);
    const float* xb2 = x + (size_t)b * Cn * Tn;
    float*       ob2 = out + (size_t)b * Cn * Tn + t0 + tq * 4;

#pragma unroll 2
    for (int rr = 0; rr < 64; ++rr) {
        const int c = rr * 16 + h2;
        const float* xrow = xb2 + (size_t)c * Tn;

        float xv[20];
        if (interior) {
            const float4* xp = reinterpret_cast<const float4*>(xrow + g0);
#pragma unroll
            for (int q = 0; q < 5; ++q) {
                const float4 a = xp[q];
                xv[4 * q + 0] = a.x; xv[4 * q + 1] = a.y;
                xv[4 * q + 2] = a.z; xv[4 * q + 3] = a.w;
            }
        } else {
#pragma unroll
            for (int i = 0; i < 20; ++i) {
                const int g = g0 + i;
                xv[i] = ((unsigned)g < (unsigned)Tn) ? xrow[g] : 0.f;
            }
        }

        // out(t = t0+tq*4+j) = sum_k wreg[k][j] * xv[j+k+1]
        float ox = 0.f, oy = 0.f, oz = 0.f, ow = 0.f;
#pragma unroll
        for (int k = 0; k < 15; ++k) {
            ox += wreg[k].x * xv[k + 1];
            oy += wreg[k].y * xv[k + 2];
            oz += wreg[k].z * xv[k + 3];
            ow += wreg[k].w * xv[k + 4];
        }
        float4 o; o.x = ox; o.y = oy; o.z = oz; o.w = ow;
        *reinterpret_cast<float4*>(ob2 + (size_t)c * Tn) = o;
    }
}

// ---------------------------------------------------------------------------
// kernel_launch — scratch plan:
//   d_ws : [0, 512K) W' bf16 (d_out is now written directly by lwc_full,
//          so scratch must NOT live there)
// ---------------------------------------------------------------------------
extern "C" void kernel_launch(void* const* d_in, const int* in_sizes, int n_in,
                              void* d_out, int out_size, void* d_ws, size_t ws_size,
                              hipStream_t stream)
{
    const float* x = (const float*)d_in[0];
    const float* W = (const float*)d_in[1];
    float* out     = (float*)d_out;

    unsigned short* Wp = (unsigned short*)d_ws;   // 512 KiB scratch

    lwc_wpad<<<dim3(Fp * Cn / 4 / 256), 256, 0, stream>>>(W, Wp);

    dim3 gF(Tn / 64, Bn);              // (64, 8) = 512 blocks
    lwc_full<<<gF, 256, 0, stream>>>(x, Wp, out);
}